// Round 20
// baseline (237.846 us; speedup 1.0000x reference)
//
#include <hip/hip_runtime.h>
#include <hip/hip_bf16.h>
#include <math.h>

#define NNODES 100000
#define NBUCK 8
#define XRANGE 12500                 // NNODES / NBUCK
#define NCHUNK 32                    // chunks per bucket for hist/scatter (256 blocks = 1/CU)
#define CAP 408192                   // per-bucket capacity: E/8 + 13 sigma
#define BCHUNK 6250                  // edges per k_bin block (LDS stash)

typedef __attribute__((ext_vector_type(8))) short bf16x8;  // 8 bf16 = 4 VGPRs
typedef __attribute__((ext_vector_type(4))) float f32x4;

// ---------------------------------------------------------------- bf16 helpers (storage bf16, math f32)
__device__ __forceinline__ float bflo(unsigned int u) {
  union { unsigned int i; float f; } v; v.i = u << 16; return v.f;
}
__device__ __forceinline__ float bfhi(unsigned int u) {
  union { unsigned int i; float f; } v; v.i = u & 0xFFFF0000u; return v.f;
}
__device__ __forceinline__ unsigned int f2bf1(float f) {
  union { float f; unsigned int i; } v; v.f = f;
  return (v.i + 0x7FFFu + ((v.i >> 16) & 1u)) >> 16;  // RNE
}
__device__ __forceinline__ unsigned int f2bf2(float a, float b) {
  return f2bf1(a) | (f2bf1(b) << 16);
}

__device__ __forceinline__ int edge_val(const void* eidx, int is64, size_t i) {
  if (is64) return (int)((const long long*)eidx)[i];
  return ((const int*)eidx)[i];
}

__device__ __forceinline__ bf16x8 cvt8(const float4& p, const float4& q) {
  union { unsigned int u[4]; bf16x8 v; } r;
  r.u[0] = f2bf2(p.x, p.y);
  r.u[1] = f2bf2(p.z, p.w);
  r.u[2] = f2bf2(q.x, q.y);
  r.u[3] = f2bf2(q.z, q.w);
  return r.v;
}

__device__ __forceinline__ bf16x8 cvtW(const float* wf) {
  union { unsigned int u[4]; bf16x8 v; } r;
  r.u[0] = f2bf2(wf[0], wf[1]);
  r.u[1] = f2bf2(wf[2], wf[3]);
  r.u[2] = f2bf2(wf[4], wf[5]);
  r.u[3] = f2bf2(wf[6], wf[7]);
  return r.v;
}

// ---------------------------------------------------------------- init: dtype-detect + zero gcur
__global__ void k_init(const void* eidx, int* flag, int* gcur) {
  int t = threadIdx.x;  // one wave
  int bad = 0;
  const unsigned long long* p = (const unsigned long long*)eidx;
  for (int i = t; i < 1024; i += 64)
    if (p[i] >> 32) bad = 1;
  unsigned long long b = __ballot(bad);
  if (t == 0) flag[0] = (b == 0ULL) ? 1 : 0;
  if (t < NBUCK) gcur[t] = 0;
}

// ---------------------------------------------------------------- binning (standalone again)
// UNFUSED from gemm1: the role-branched fused kernel compiled at VGPR 36-52
// regardless of launch_bounds — the compiler sank gemm1's double-buffer
// loads (no pipeline). Fused binmm = 137us vs standalone gemm1(85)+bin(28).
__global__ void k_bin(const void* eidx, const int* __restrict__ flag, int* gcur,
                      int* __restrict__ sArr, unsigned short* __restrict__ dArr, int E) {
  __shared__ unsigned int s_sb[BCHUNK];    // s | bk<<17
  __shared__ unsigned short s_dl[BCHUNK];  // d - bk*XRANGE
  __shared__ int bbase[NBUCK], lcur[NBUCK], wcnt[4][NBUCK];
  int is64 = flag[0];
  int beg = blockIdx.x * BCHUNK;
  int end = min(beg + BCHUNK, E);
  int cnt = end - beg;
  int lane = threadIdx.x & 63, wid = threadIdx.x >> 6;

  // phase A: read edges once, stash to LDS, ballot-count per wave
  int cl = 0;
  for (int i = threadIdx.x; i < cnt; i += 256) {
    int e = beg + i;
    int s = edge_val(eidx, is64, e);
    int d = edge_val(eidx, is64, (size_t)E + e);
    int bk = d / XRANGE;
    s_sb[i] = (unsigned int)s | ((unsigned int)bk << 17);
    s_dl[i] = (unsigned short)(d - bk * XRANGE);
    #pragma unroll
    for (int b = 0; b < NBUCK; ++b) {
      unsigned long long m = __ballot(bk == b);
      if (lane == b) cl += __popcll(m);
    }
  }
  if (lane < NBUCK) wcnt[wid][lane] = cl;
  __syncthreads();
  if (threadIdx.x < NBUCK) {
    int t = wcnt[0][threadIdx.x] + wcnt[1][threadIdx.x] +
            wcnt[2][threadIdx.x] + wcnt[3][threadIdx.x];
    bbase[threadIdx.x] = atomicAdd(&gcur[threadIdx.x], t);
    lcur[threadIdx.x] = 0;
  }
  __syncthreads();

  // phase B: ballot-rank placement from LDS
  for (int i = threadIdx.x; i < cnt; i += 256) {
    unsigned int sb = s_sb[i];
    int bk = (int)(sb >> 17);
    int s = (int)(sb & 0x1FFFFu);
    unsigned short dl = s_dl[i];
    #pragma unroll
    for (int b = 0; b < NBUCK; ++b) {
      unsigned long long m = __ballot(bk == b);
      int c = __popcll(m);
      if (!c) continue;
      int leader = __ffsll((unsigned long long)m) - 1;
      int base = 0;
      if (lane == leader) base = atomicAdd(&lcur[b], c);  // LDS atomic
      base = __shfl(base, leader);
      if (bk == b) {
        int rank = __popcll(m & ((1ULL << lane) - 1));
        int gpos = bbase[b] + base + rank;
        if (gpos < CAP) {
          sArr[(size_t)b * CAP + gpos] = s;
          dArr[(size_t)b * CAP + gpos] = dl;
        }
      }
    }
  }
}

// ---------------------------------------------------------------- histogram (LDS, no device atomics)
__global__ void k_hist(const int* __restrict__ gcur, const unsigned short* __restrict__ dArr,
                       int* __restrict__ cntc) {
  int b = blockIdx.x & (NBUCK - 1);
  int c = blockIdx.x >> 3;
  __shared__ int h[XRANGE];
  for (int i = threadIdx.x; i < XRANGE; i += 256) h[i] = 0;
  __syncthreads();
  int nE = min(gcur[b], CAP);
  int ce = (nE + NCHUNK - 1) / NCHUNK;
  int beg = c * ce, end = min(beg + ce, nE);
  const unsigned short* dp = dArr + (size_t)b * CAP;
  for (int e = beg + threadIdx.x; e < end; e += 256)
    atomicAdd(&h[dp[e]], 1);
  __syncthreads();
  int lo = b * XRANGE;
  for (int i = threadIdx.x; i < XRANGE; i += 256)
    cntc[(size_t)c * NNODES + lo + i] = h[i];
}

// ---------------------------------------------------------------- degree -> dis (+ block sums for scan)
__global__ void k_dis(const int* __restrict__ cntc, int* __restrict__ tot,
                      float* __restrict__ dis, int* __restrict__ bsum, int n) {
  int i = blockIdx.x * 256 + threadIdx.x;
  int t = 0;
  if (i < n) {
    #pragma unroll
    for (int c = 0; c < NCHUNK; ++c) t += cntc[(size_t)c * NNODES + i];
    tot[i] = t;
    dis[i] = rsqrtf((float)(t + 1));  // +1 = self loop
  }
  int v = t;
  #pragma unroll
  for (int d = 32; d > 0; d >>= 1) v += __shfl_down(v, d);
  __shared__ int ws4[4];
  if ((threadIdx.x & 63) == 0) ws4[threadIdx.x >> 6] = v;
  __syncthreads();
  if (threadIdx.x == 0) bsum[blockIdx.x] = ws4[0] + ws4[1] + ws4[2] + ws4[3];
}

// ---------------------------------------------------------------- GEMM1: x[100K,512] @ W1 -> gb1 (bf16, dis-scaled)
// Standalone R13-proven body: 32 rows/wave, one-kc-ahead register double
// buffer, lb(64,4) -> VGPR ~130 and the compiler KEEPS the prefetch
// pipeline (fused role-branch version collapsed to VGPR 52, serial loads).
__global__ __launch_bounds__(64, 4) void k_gemm1(const float* __restrict__ x,
                                                 const float* __restrict__ W,
                                                 const float* __restrict__ dis,
                                                 unsigned short* __restrict__ gb, int nrows) {
  int lane = threadIdx.x;       // single wave
  int row0 = blockIdx.x * 32;   // 100000 % 32 == 0 -> no tail guards
  int q8 = lane >> 4;           // k-octet selector (0..3)
  int jm = lane & 15;           // B col j == A row-in-tile m
  const float4* x4 = (const float4*)x;
  size_t xb0 = (size_t)(row0 + jm) * 128 + q8 * 2;        // tile 0 base (float4 units)
  size_t xb1 = (size_t)(row0 + 16 + jm) * 128 + q8 * 2;   // tile 1 base

  float4 va0 = x4[xb0], va1 = x4[xb0 + 1];
  float4 va2 = x4[xb1], va3 = x4[xb1 + 1];
  float wf[8];
  #pragma unroll
  for (int i = 0; i < 8; ++i)
    wf[i] = W[(size_t)(q8 * 8 + i) * 16 + jm];

  f32x4 acc0 = {0.f, 0.f, 0.f, 0.f}, acc1 = {0.f, 0.f, 0.f, 0.f};

  #pragma unroll
  for (int kc = 0; kc < 16; ++kc) {
    float4 vn0, vn1, vn2, vn3;
    float wn[8];
    if (kc + 1 < 16) {
      vn0 = x4[xb0 + (kc + 1) * 8];
      vn1 = x4[xb0 + (kc + 1) * 8 + 1];
      vn2 = x4[xb1 + (kc + 1) * 8];
      vn3 = x4[xb1 + (kc + 1) * 8 + 1];
      #pragma unroll
      for (int i = 0; i < 8; ++i)
        wn[i] = W[(size_t)((kc + 1) * 32 + q8 * 8 + i) * 16 + jm];
    }
    bf16x8 bfr = cvtW(wf);
    acc0 = __builtin_amdgcn_mfma_f32_16x16x32_bf16(cvt8(va0, va1), bfr, acc0, 0, 0, 0);
    acc1 = __builtin_amdgcn_mfma_f32_16x16x32_bf16(cvt8(va2, va3), bfr, acc1, 0, 0, 0);
    if (kc + 1 < 16) {
      va0 = vn0; va1 = vn1; va2 = vn2; va3 = vn3;
      #pragma unroll
      for (int i = 0; i < 8; ++i) wf[i] = wn[i];
    }
  }

  // epilogue: D[row = t*16 + q8*4 + r][jm]; dis broadcast via shuffle
  float dis_own = dis[row0 + min(lane, 31)];
  #pragma unroll
  for (int r = 0; r < 4; ++r) {
    int rl0 = q8 * 4 + r;
    float d0 = __shfl(dis_own, rl0);
    gb[(size_t)(row0 + rl0) * 16 + jm] = (unsigned short)f2bf1(acc0[r] * d0);
    int rl1 = 16 + rl0;
    float d1 = __shfl(dis_own, rl1);
    gb[(size_t)(row0 + rl1) * 16 + jm] = (unsigned short)f2bf1(acc1[r] * d1);
  }
}

// fused scan: every block replicates the 391-entry partials scan, then its
// per-node local scan, then walks the 32 chunk planes into cursor bases.
__global__ void k_scan_fc(const int* __restrict__ tot, const int* __restrict__ bsum,
                          int* __restrict__ rowptr, int* __restrict__ cntc, int n, int nb) {
  __shared__ int ps[512];
  __shared__ int s[256];
  int t = threadIdx.x;
  ps[t] = (t < nb) ? bsum[t] : 0;
  ps[t + 256] = (t + 256 < nb) ? bsum[t + 256] : 0;
  __syncthreads();
  for (int d = 1; d < 512; d <<= 1) {
    int u0 = (t >= d) ? ps[t - d] : 0;
    int u1 = (t + 256 >= d) ? ps[t + 256 - d] : 0;
    __syncthreads();
    ps[t] += u0;
    ps[t + 256] += u1;
    __syncthreads();
  }
  int bex = (blockIdx.x == 0) ? 0 : ps[blockIdx.x - 1];
  if (blockIdx.x == 0 && t == 0) rowptr[n] = ps[nb - 1];  // total

  int idx = blockIdx.x * 256 + t;
  int v = (idx < n) ? tot[idx] : 0;
  s[t] = v;
  __syncthreads();
  for (int d = 1; d < 256; d <<= 1) {
    int u = (t >= d) ? s[t - d] : 0;
    __syncthreads();
    s[t] += u;
    __syncthreads();
  }
  if (idx < n) {
    int run = bex + s[t] - v;
    rowptr[idx] = run;
    #pragma unroll
    for (int c = 0; c < NCHUNK; ++c) {
      size_t id2 = (size_t)c * NNODES + idx;
      int tc = cntc[id2];
      cntc[id2] = run;
      run += tc;
    }
  }
}

// ---------------------------------------------------------------- scatter (LDS cursors)
__global__ void k_scatter(const int* __restrict__ gcur, const int* __restrict__ sArr,
                          const unsigned short* __restrict__ dArr,
                          const int* __restrict__ cntc, int* __restrict__ col) {
  int b = blockIdx.x & (NBUCK - 1);
  int c = blockIdx.x >> 3;
  __shared__ int cur[XRANGE];
  int lo = b * XRANGE;
  for (int i = threadIdx.x; i < XRANGE; i += 256)
    cur[i] = cntc[(size_t)c * NNODES + lo + i];
  __syncthreads();
  int nE = min(gcur[b], CAP);
  int ce = (nE + NCHUNK - 1) / NCHUNK;
  int beg = c * ce, end = min(beg + ce, nE);
  const int* sp = sArr + (size_t)b * CAP;
  const unsigned short* dp = dArr + (size_t)b * CAP;
  for (int e = beg + threadIdx.x; e < end; e += 256) {
    int d = dp[e];
    int pos = atomicAdd(&cur[d], 1);  // LDS atomic
    col[pos] = sp[e];
  }
}

// ---------------------------------------------------------------- GEMM2: o1[100K,16] @ W2 -> gb2 (bf16, pre-scaled)
__global__ void k_gemm2(const float* __restrict__ o1, const float* __restrict__ W,
                        const float* __restrict__ dis, unsigned int* __restrict__ gb, int nrows) {
  int row = blockIdx.x * blockDim.x + threadIdx.x;
  if (row >= nrows) return;
  const float4* xr = (const float4*)(o1 + (size_t)row * 16);
  float4 x0 = xr[0], x1 = xr[1], x2 = xr[2], x3 = xr[3];
  float xv[16] = {x0.x, x0.y, x0.z, x0.w, x1.x, x1.y, x1.z, x1.w,
                  x2.x, x2.y, x2.z, x2.w, x3.x, x3.y, x3.z, x3.w};
  float acc[16];
  #pragma unroll
  for (int j = 0; j < 16; ++j) acc[j] = 0.f;
  #pragma unroll
  for (int k = 0; k < 16; ++k) {
    const float* wr = W + (size_t)k * 16;
    #pragma unroll
    for (int j = 0; j < 16; ++j)
      acc[j] = fmaf(xv[k], wr[j], acc[j]);
  }
  float dd = dis[row];
  uint4 pa, pb;
  pa.x = f2bf2(acc[0] * dd, acc[1] * dd);
  pa.y = f2bf2(acc[2] * dd, acc[3] * dd);
  pa.z = f2bf2(acc[4] * dd, acc[5] * dd);
  pa.w = f2bf2(acc[6] * dd, acc[7] * dd);
  pb.x = f2bf2(acc[8] * dd, acc[9] * dd);
  pb.y = f2bf2(acc[10] * dd, acc[11] * dd);
  pb.z = f2bf2(acc[12] * dd, acc[13] * dd);
  pb.w = f2bf2(acc[14] * dd, acc[15] * dd);
  uint4* g4 = (uint4*)gb;
  g4[(size_t)row * 2] = pa;
  g4[(size_t)row * 2 + 1] = pb;
}

// ---------------------------------------------------------------- aggregation: 2 nodes per wave
__device__ __forceinline__ void gather8v2(const uint4* gp, const int* __restrict__ col,
                                          int beg, int end, int h, int slot, float* acc) {
  #pragma unroll
  for (int j = 0; j < 8; ++j) acc[j] = 0.f;
  for (int e = beg + slot; e < end; e += 16) {
    int s = col[e];
    uint4 v = gp[(size_t)s * 2 + h];
    acc[0] += bflo(v.x); acc[1] += bfhi(v.x);
    acc[2] += bflo(v.y); acc[3] += bfhi(v.y);
    acc[4] += bflo(v.z); acc[5] += bfhi(v.z);
    acc[6] += bflo(v.w); acc[7] += bfhi(v.w);
  }
  #pragma unroll
  for (int d = 2; d < 32; d <<= 1) {  // slot bits = lane bits 1..4
    #pragma unroll
    for (int j = 0; j < 8; ++j) acc[j] += __shfl_xor(acc[j], d);
  }
}

// layer-1 agg: z = relu(dis*(sum + self) + b1) -> o1 (f32)
__global__ void k_agg1(const unsigned int* __restrict__ gb, const int* __restrict__ col,
                       const int* __restrict__ rowptr, const float* __restrict__ dis,
                       const float* __restrict__ bias, float* __restrict__ o1) {
  int wid = threadIdx.x >> 6;
  int lane = threadIdx.x & 63;
  int n2 = lane >> 5;
  int node = blockIdx.x * 8 + wid * 2 + n2;
  if (node >= NNODES) return;
  int rem = lane & 31;
  int h = rem & 1, slot = rem >> 1;
  const uint4* gp = (const uint4*)gb;
  float acc[8];
  gather8v2(gp, col, rowptr[node], rowptr[node + 1], h, slot, acc);
  uint4 sv = gp[(size_t)node * 2 + h];
  acc[0] += bflo(sv.x); acc[1] += bfhi(sv.x);
  acc[2] += bflo(sv.y); acc[3] += bfhi(sv.y);
  acc[4] += bflo(sv.z); acc[5] += bfhi(sv.z);
  acc[6] += bflo(sv.w); acc[7] += bfhi(sv.w);
  float dd = dis[node];
  const float4* b4 = (const float4*)bias;
  float4 ba = b4[2 * h], bb = b4[2 * h + 1];
  float z0 = fmaxf(fmaf(dd, acc[0], ba.x), 0.f);
  float z1 = fmaxf(fmaf(dd, acc[1], ba.y), 0.f);
  float z2 = fmaxf(fmaf(dd, acc[2], ba.z), 0.f);
  float z3 = fmaxf(fmaf(dd, acc[3], ba.w), 0.f);
  float z4 = fmaxf(fmaf(dd, acc[4], bb.x), 0.f);
  float z5 = fmaxf(fmaf(dd, acc[5], bb.y), 0.f);
  float z6 = fmaxf(fmaf(dd, acc[6], bb.z), 0.f);
  float z7 = fmaxf(fmaf(dd, acc[7], bb.w), 0.f);
  if (slot == 0) {
    float4* o4 = (float4*)o1;
    o4[(size_t)node * 4 + 2 * h] = make_float4(z0, z1, z2, z3);
    o4[(size_t)node * 4 + 2 * h + 1] = make_float4(z4, z5, z6, z7);
  }
}

// layer-2 agg: z = dis*(sum + self) + b2 -> log_softmax -> out (f32)
__global__ void k_agg2(const unsigned int* __restrict__ gb, const int* __restrict__ col,
                       const int* __restrict__ rowptr, const float* __restrict__ dis,
                       const float* __restrict__ bias, float* __restrict__ out) {
  int wid = threadIdx.x >> 6;
  int lane = threadIdx.x & 63;
  int n2 = lane >> 5;
  int node = blockIdx.x * 8 + wid * 2 + n2;
  if (node >= NNODES) return;
  int rem = lane & 31;
  int h = rem & 1, slot = rem >> 1;
  const uint4* gp = (const uint4*)gb;
  float acc[8];
  gather8v2(gp, col, rowptr[node], rowptr[node + 1], h, slot, acc);
  uint4 sv = gp[(size_t)node * 2 + h];
  acc[0] += bflo(sv.x); acc[1] += bfhi(sv.x);
  acc[2] += bflo(sv.y); acc[3] += bfhi(sv.y);
  acc[4] += bflo(sv.z); acc[5] += bfhi(sv.z);
  acc[6] += bflo(sv.w); acc[7] += bfhi(sv.w);
  float dd = dis[node];
  const float4* b4 = (const float4*)bias;
  float4 ba = b4[2 * h], bb = b4[2 * h + 1];
  float z[8];
  z[0] = fmaf(dd, acc[0], ba.x); z[1] = fmaf(dd, acc[1], ba.y);
  z[2] = fmaf(dd, acc[2], ba.z); z[3] = fmaf(dd, acc[3], ba.w);
  z[4] = fmaf(dd, acc[4], bb.x); z[5] = fmaf(dd, acc[5], bb.y);
  z[6] = fmaf(dd, acc[6], bb.z); z[7] = fmaf(dd, acc[7], bb.w);
  float m = z[0];
  #pragma unroll
  for (int j = 1; j < 8; ++j) m = fmaxf(m, z[j]);
  m = fmaxf(m, __shfl_xor(m, 1));  // combine halves (within pair)
  float se = 0.f;
  #pragma unroll
  for (int j = 0; j < 8; ++j) se += expf(z[j] - m);
  se += __shfl_xor(se, 1);
  float lg = m + logf(se);
  if (slot == 0) {
    float4* o4 = (float4*)out;
    o4[(size_t)node * 4 + 2 * h] = make_float4(z[0] - lg, z[1] - lg, z[2] - lg, z[3] - lg);
    o4[(size_t)node * 4 + 2 * h + 1] = make_float4(z[4] - lg, z[5] - lg, z[6] - lg, z[7] - lg);
  }
}

// ---------------------------------------------------------------- launch
extern "C" void kernel_launch(void* const* d_in, const int* in_sizes, int n_in,
                              void* d_out, int out_size, void* d_ws, size_t ws_size,
                              hipStream_t stream) {
  const float* x  = (const float*)d_in[0];
  const void*  ei = d_in[1];
  const float* W1 = (const float*)d_in[2];
  const float* b1 = (const float*)d_in[3];
  const float* W2 = (const float*)d_in[4];
  const float* b2 = (const float*)d_in[5];
  float* out = (float*)d_out;

  const int n = NNODES;
  const int E = in_sizes[1] / 2;

  char* ws = (char*)d_ws;
  size_t off = 0;
  auto alloc = [&](size_t bytes) -> void* {
    void* p = ws + off;
    off = (off + bytes + 255) & ~(size_t)255;
    return p;
  };
  int*            flag   = (int*)            alloc(256);
  int*            gcur   = (int*)            alloc(256);
  int*            sArr   = (int*)            alloc((size_t)NBUCK * CAP * 4);  // 13.1 MB
  unsigned short* dArr   = (unsigned short*) alloc((size_t)NBUCK * CAP * 2);  // 6.5 MB
  int*            cntc   = (int*)            alloc((size_t)NCHUNK * n * 4);   // 12.8 MB
  int*            tot    = (int*)            alloc((size_t)n * 4);
  float*          dis    = (float*)          alloc((size_t)n * 4);
  int*            rowptr = (int*)            alloc((size_t)(n + 1) * 4);
  int*            bsum   = (int*)            alloc(4096);
  int*            col    = (int*)            alloc((size_t)E * 4);            // 12.8 MB
  unsigned short* gb1    = (unsigned short*) alloc((size_t)n * 16 * 2);       // 3.2 MB bf16
  // overlays (dead after k_scatter): o1 (6.4 MB f32) in sArr (13.1 MB); gb2 (3.2 MB) in dArr (6.5 MB)
  float*          o1  = (float*)sArr;
  unsigned int*   gb2 = (unsigned int*)dArr;
  (void)ws_size; (void)n_in; (void)out_size;

  int nb = (n + 255) / 256;  // 391 <= 512

  k_init<<<1, 64, 0, stream>>>(ei, flag, gcur);
  k_bin<<<(E + BCHUNK - 1) / BCHUNK, 256, 0, stream>>>(ei, flag, gcur, sArr, dArr, E);
  k_hist<<<NBUCK * NCHUNK, 256, 0, stream>>>(gcur, dArr, cntc);
  k_dis<<<nb, 256, 0, stream>>>(cntc, tot, dis, bsum, n);

  // GEMM1 needs dis (epilogue scaling).
  k_gemm1<<<n / 32, 64, 0, stream>>>(x, W1, dis, gb1, n);

  k_scan_fc<<<nb, 256, 0, stream>>>(tot, bsum, rowptr, cntc, n, nb);
  k_scatter<<<NBUCK * NCHUNK, 256, 0, stream>>>(gcur, sArr, dArr, cntc, col);

  k_agg1<<<(n + 7) / 8, 256, 0, stream>>>((const unsigned int*)gb1, col, rowptr, dis, b1, o1);
  k_gemm2<<<(n + 255) / 256, 256, 0, stream>>>(o1, W2, dis, (unsigned int*)gb2, n);
  k_agg2<<<(n + 7) / 8, 256, 0, stream>>>(gb2, col, rowptr, dis, b2, out);
}

// Round 21
// 205.376 us; speedup vs baseline: 1.1581x; 1.1581x over previous
//
#include <hip/hip_runtime.h>
#include <hip/hip_bf16.h>
#include <math.h>

#define NNODES 100000
#define NBUCK 8
#define XRANGE 12500                 // NNODES / NBUCK
#define NCHUNK 32                    // chunks per bucket for hist/scatter (256 blocks = 1/CU)
#define CAP 408192                   // per-bucket capacity: E/8 + 13 sigma
#define BCHUNK 3125                  // edges per bin-role block: stash 18.8 KB -> 8 blocks/CU LDS cap
#define GTILES (NNODES / 32)         // 3125 gemm wave-tiles of 32 rows

typedef __attribute__((ext_vector_type(8))) short bf16x8;  // 8 bf16 = 4 VGPRs
typedef __attribute__((ext_vector_type(4))) float f32x4;

// ---------------------------------------------------------------- bf16 helpers (storage bf16, math f32)
__device__ __forceinline__ float bflo(unsigned int u) {
  union { unsigned int i; float f; } v; v.i = u << 16; return v.f;
}
__device__ __forceinline__ float bfhi(unsigned int u) {
  union { unsigned int i; float f; } v; v.i = u & 0xFFFF0000u; return v.f;
}
__device__ __forceinline__ unsigned int f2bf1(float f) {
  union { float f; unsigned int i; } v; v.f = f;
  return (v.i + 0x7FFFu + ((v.i >> 16) & 1u)) >> 16;  // RNE
}
__device__ __forceinline__ unsigned int f2bf2(float a, float b) {
  return f2bf1(a) | (f2bf1(b) << 16);
}

__device__ __forceinline__ int edge_val(const void* eidx, int is64, size_t i) {
  if (is64) return (int)((const long long*)eidx)[i];
  return ((const int*)eidx)[i];
}

__device__ __forceinline__ bf16x8 cvt8(const float4& p, const float4& q) {
  union { unsigned int u[4]; bf16x8 v; } r;
  r.u[0] = f2bf2(p.x, p.y);
  r.u[1] = f2bf2(p.z, p.w);
  r.u[2] = f2bf2(q.x, q.y);
  r.u[3] = f2bf2(q.z, q.w);
  return r.v;
}

__device__ __forceinline__ bf16x8 cvtW(const float* wf) {
  union { unsigned int u[4]; bf16x8 v; } r;
  r.u[0] = f2bf2(wf[0], wf[1]);
  r.u[1] = f2bf2(wf[2], wf[3]);
  r.u[2] = f2bf2(wf[4], wf[5]);
  r.u[3] = f2bf2(wf[6], wf[7]);
  return r.v;
}

// ---------------------------------------------------------------- init: dtype-detect + zero gcur
__global__ void k_init(const void* eidx, int* flag, int* gcur) {
  int t = threadIdx.x;  // one wave
  int bad = 0;
  const unsigned long long* p = (const unsigned long long*)eidx;
  for (int i = t; i < 1024; i += 64)
    if (p[i] >> 32) bad = 1;
  unsigned long long b = __ballot(bad);
  if (t == 0) flag[0] = (b == 0ULL) ? 1 : 0;
  if (t < NBUCK) gcur[t] = 0;
}

// ---------------------------------------------------------------- FUSED bin || gemm1
// R19 structure (best so far, 222us; unfused R20 = 238 -> overlap is worth
// more than the lost register pipeline). This round: BCHUNK 6250->3125 cuts
// the bin stash 37.9->18.8 KB, lifting the LDS cap 4->8 blocks/CU; roles
// regrouped 7 = 3 gemm + 4 bin (binBlocks 512->1024); grid 1827 = 7.1/CU
// fully co-resident. VGPR stays ~36-52 (<=64) so waves aren't the cap.
__global__ void k_binmm(const void* eidx, const int* __restrict__ flag, int* gcur,
                        int* __restrict__ sArr, unsigned short* __restrict__ dArr,
                        int E, int binBlocks,
                        const float* __restrict__ x, const float* __restrict__ W,
                        unsigned short* __restrict__ gb, int gemmBlocks) {
  __shared__ unsigned int s_sb[BCHUNK];    // bin: s | bk<<17  (12.5 KB)
  __shared__ unsigned short s_dl[BCHUNK];  // bin: d - bk*XRANGE (6.25 KB)
  __shared__ int bbase[NBUCK], lcur[NBUCK], wcnt[4][NBUCK];

  int grp = blockIdx.x / 7, role = blockIdx.x % 7;
  if (role < 3) {
    // ---------------- gemm1 role (unscaled output; dis applied in k_dis) ----------------
    int gid = grp * 3 + role;
    if (gid >= gemmBlocks) return;
    int wid = threadIdx.x >> 6;
    int tile = gid * 4 + wid;
    if (tile >= GTILES) return;
    int lane = threadIdx.x & 63;
    int row0 = tile * 32;
    int q8 = lane >> 4;           // k-octet selector (0..3)
    int jm = lane & 15;           // B col j == A row-in-tile m
    const float4* x4 = (const float4*)x;
    size_t xb0 = (size_t)(row0 + jm) * 128 + q8 * 2;
    size_t xb1 = (size_t)(row0 + 16 + jm) * 128 + q8 * 2;

    float4 va0 = x4[xb0], va1 = x4[xb0 + 1];
    float4 va2 = x4[xb1], va3 = x4[xb1 + 1];
    float wf[8];
    #pragma unroll
    for (int i = 0; i < 8; ++i)
      wf[i] = W[(size_t)(q8 * 8 + i) * 16 + jm];

    f32x4 acc0 = {0.f, 0.f, 0.f, 0.f}, acc1 = {0.f, 0.f, 0.f, 0.f};
    #pragma unroll
    for (int kc = 0; kc < 16; ++kc) {
      float4 vn0, vn1, vn2, vn3;
      float wn[8];
      if (kc + 1 < 16) {
        vn0 = x4[xb0 + (kc + 1) * 8];
        vn1 = x4[xb0 + (kc + 1) * 8 + 1];
        vn2 = x4[xb1 + (kc + 1) * 8];
        vn3 = x4[xb1 + (kc + 1) * 8 + 1];
        #pragma unroll
        for (int i = 0; i < 8; ++i)
          wn[i] = W[(size_t)((kc + 1) * 32 + q8 * 8 + i) * 16 + jm];
      }
      bf16x8 bfr = cvtW(wf);
      acc0 = __builtin_amdgcn_mfma_f32_16x16x32_bf16(cvt8(va0, va1), bfr, acc0, 0, 0, 0);
      acc1 = __builtin_amdgcn_mfma_f32_16x16x32_bf16(cvt8(va2, va3), bfr, acc1, 0, 0, 0);
      if (kc + 1 < 16) {
        va0 = vn0; va1 = vn1; va2 = vn2; va3 = vn3;
        #pragma unroll
        for (int i = 0; i < 8; ++i) wf[i] = wn[i];
      }
    }
    // unscaled epilogue: D[row = t*16 + q8*4 + r][jm]
    #pragma unroll
    for (int r = 0; r < 4; ++r) {
      int rl0 = q8 * 4 + r;
      gb[(size_t)(row0 + rl0) * 16 + jm] = (unsigned short)f2bf1(acc0[r]);
      gb[(size_t)(row0 + 16 + rl0) * 16 + jm] = (unsigned short)f2bf1(acc1[r]);
    }
    return;
  }

  // ---------------- bin role (LDS stash, single global edge read) ----------------
  int bid = grp * 4 + (role - 3);
  if (bid >= binBlocks) return;
  int is64 = flag[0];
  int beg = bid * BCHUNK;
  int end = min(beg + BCHUNK, E);
  int cnt = end - beg;
  int lane = threadIdx.x & 63, wid = threadIdx.x >> 6;

  // phase A: read edges once, stash to LDS, ballot-count per wave
  int cl = 0;
  for (int i = threadIdx.x; i < cnt; i += 256) {
    int e = beg + i;
    int s = edge_val(eidx, is64, e);
    int d = edge_val(eidx, is64, (size_t)E + e);
    int bk = d / XRANGE;
    s_sb[i] = (unsigned int)s | ((unsigned int)bk << 17);
    s_dl[i] = (unsigned short)(d - bk * XRANGE);
    #pragma unroll
    for (int b = 0; b < NBUCK; ++b) {
      unsigned long long m = __ballot(bk == b);
      if (lane == b) cl += __popcll(m);   // low lanes exit the loop last
    }
  }
  if (lane < NBUCK) wcnt[wid][lane] = cl;
  __syncthreads();
  if (threadIdx.x < NBUCK) {
    int t = wcnt[0][threadIdx.x] + wcnt[1][threadIdx.x] +
            wcnt[2][threadIdx.x] + wcnt[3][threadIdx.x];
    bbase[threadIdx.x] = atomicAdd(&gcur[threadIdx.x], t);
    lcur[threadIdx.x] = 0;
  }
  __syncthreads();

  // phase B: ballot-rank placement from LDS
  for (int i = threadIdx.x; i < cnt; i += 256) {
    unsigned int sb = s_sb[i];
    int bk = (int)(sb >> 17);
    int s = (int)(sb & 0x1FFFFu);
    unsigned short dl = s_dl[i];
    #pragma unroll
    for (int b = 0; b < NBUCK; ++b) {
      unsigned long long m = __ballot(bk == b);
      int c = __popcll(m);
      if (!c) continue;
      int leader = __ffsll((unsigned long long)m) - 1;
      int base = 0;
      if (lane == leader) base = atomicAdd(&lcur[b], c);  // LDS atomic
      base = __shfl(base, leader);
      if (bk == b) {
        int rank = __popcll(m & ((1ULL << lane) - 1));
        int gpos = bbase[b] + base + rank;
        if (gpos < CAP) {
          sArr[(size_t)b * CAP + gpos] = s;
          dArr[(size_t)b * CAP + gpos] = dl;
        }
      }
    }
  }
}

// ---------------------------------------------------------------- histogram (LDS, no device atomics)
__global__ void k_hist(const int* __restrict__ gcur, const unsigned short* __restrict__ dArr,
                       int* __restrict__ cntc) {
  int b = blockIdx.x & (NBUCK - 1);
  int c = blockIdx.x >> 3;
  __shared__ int h[XRANGE];
  for (int i = threadIdx.x; i < XRANGE; i += 256) h[i] = 0;
  __syncthreads();
  int nE = min(gcur[b], CAP);
  int ce = (nE + NCHUNK - 1) / NCHUNK;
  int beg = c * ce, end = min(beg + ce, nE);
  const unsigned short* dp = dArr + (size_t)b * CAP;
  for (int e = beg + threadIdx.x; e < end; e += 256)
    atomicAdd(&h[dp[e]], 1);
  __syncthreads();
  int lo = b * XRANGE;
  for (int i = threadIdx.x; i < XRANGE; i += 256)
    cntc[(size_t)c * NNODES + lo + i] = h[i];
}

// ---------------------------------------------------------------- degree -> dis, and SCALE gb1 in place
__global__ void k_dis(const int* __restrict__ cntc, int* __restrict__ tot,
                      float* __restrict__ dis, int* __restrict__ bsum,
                      unsigned int* __restrict__ gb1, int n) {
  int i = blockIdx.x * 256 + threadIdx.x;
  int t = 0;
  if (i < n) {
    #pragma unroll
    for (int c = 0; c < NCHUNK; ++c) t += cntc[(size_t)c * NNODES + i];
    tot[i] = t;
    float dd = rsqrtf((float)(t + 1));  // +1 = self loop
    dis[i] = dd;
    uint4* g4 = (uint4*)gb1;
    uint4 pa = g4[(size_t)i * 2], pb = g4[(size_t)i * 2 + 1];
    pa.x = f2bf2(bflo(pa.x) * dd, bfhi(pa.x) * dd);
    pa.y = f2bf2(bflo(pa.y) * dd, bfhi(pa.y) * dd);
    pa.z = f2bf2(bflo(pa.z) * dd, bfhi(pa.z) * dd);
    pa.w = f2bf2(bflo(pa.w) * dd, bfhi(pa.w) * dd);
    pb.x = f2bf2(bflo(pb.x) * dd, bfhi(pb.x) * dd);
    pb.y = f2bf2(bflo(pb.y) * dd, bfhi(pb.y) * dd);
    pb.z = f2bf2(bflo(pb.z) * dd, bfhi(pb.z) * dd);
    pb.w = f2bf2(bflo(pb.w) * dd, bfhi(pb.w) * dd);
    g4[(size_t)i * 2] = pa;
    g4[(size_t)i * 2 + 1] = pb;
  }
  int v = t;
  #pragma unroll
  for (int d = 32; d > 0; d >>= 1) v += __shfl_down(v, d);
  __shared__ int ws4[4];
  if ((threadIdx.x & 63) == 0) ws4[threadIdx.x >> 6] = v;
  __syncthreads();
  if (threadIdx.x == 0) bsum[blockIdx.x] = ws4[0] + ws4[1] + ws4[2] + ws4[3];
}

// fused scan: every block replicates the 391-entry partials scan, then its
// per-node local scan, then walks the 32 chunk planes into cursor bases.
__global__ void k_scan_fc(const int* __restrict__ tot, const int* __restrict__ bsum,
                          int* __restrict__ rowptr, int* __restrict__ cntc, int n, int nb) {
  __shared__ int ps[512];
  __shared__ int s[256];
  int t = threadIdx.x;
  ps[t] = (t < nb) ? bsum[t] : 0;
  ps[t + 256] = (t + 256 < nb) ? bsum[t + 256] : 0;
  __syncthreads();
  for (int d = 1; d < 512; d <<= 1) {
    int u0 = (t >= d) ? ps[t - d] : 0;
    int u1 = (t + 256 >= d) ? ps[t + 256 - d] : 0;
    __syncthreads();
    ps[t] += u0;
    ps[t + 256] += u1;
    __syncthreads();
  }
  int bex = (blockIdx.x == 0) ? 0 : ps[blockIdx.x - 1];
  if (blockIdx.x == 0 && t == 0) rowptr[n] = ps[nb - 1];  // total

  int idx = blockIdx.x * 256 + t;
  int v = (idx < n) ? tot[idx] : 0;
  s[t] = v;
  __syncthreads();
  for (int d = 1; d < 256; d <<= 1) {
    int u = (t >= d) ? s[t - d] : 0;
    __syncthreads();
    s[t] += u;
    __syncthreads();
  }
  if (idx < n) {
    int run = bex + s[t] - v;
    rowptr[idx] = run;
    #pragma unroll
    for (int c = 0; c < NCHUNK; ++c) {
      size_t id2 = (size_t)c * NNODES + idx;
      int tc = cntc[id2];
      cntc[id2] = run;
      run += tc;
    }
  }
}

// ---------------------------------------------------------------- scatter (LDS cursors)
__global__ void k_scatter(const int* __restrict__ gcur, const int* __restrict__ sArr,
                          const unsigned short* __restrict__ dArr,
                          const int* __restrict__ cntc, int* __restrict__ col) {
  int b = blockIdx.x & (NBUCK - 1);
  int c = blockIdx.x >> 3;
  __shared__ int cur[XRANGE];
  int lo = b * XRANGE;
  for (int i = threadIdx.x; i < XRANGE; i += 256)
    cur[i] = cntc[(size_t)c * NNODES + lo + i];
  __syncthreads();
  int nE = min(gcur[b], CAP);
  int ce = (nE + NCHUNK - 1) / NCHUNK;
  int beg = c * ce, end = min(beg + ce, nE);
  const int* sp = sArr + (size_t)b * CAP;
  const unsigned short* dp = dArr + (size_t)b * CAP;
  for (int e = beg + threadIdx.x; e < end; e += 256) {
    int d = dp[e];
    int pos = atomicAdd(&cur[d], 1);  // LDS atomic
    col[pos] = sp[e];
  }
}

// ---------------------------------------------------------------- GEMM2: o1[100K,16] @ W2 -> gb2 (bf16, pre-scaled)
__global__ void k_gemm2(const float* __restrict__ o1, const float* __restrict__ W,
                        const float* __restrict__ dis, unsigned int* __restrict__ gb, int nrows) {
  int row = blockIdx.x * blockDim.x + threadIdx.x;
  if (row >= nrows) return;
  const float4* xr = (const float4*)(o1 + (size_t)row * 16);
  float4 x0 = xr[0], x1 = xr[1], x2 = xr[2], x3 = xr[3];
  float xv[16] = {x0.x, x0.y, x0.z, x0.w, x1.x, x1.y, x1.z, x1.w,
                  x2.x, x2.y, x2.z, x2.w, x3.x, x3.y, x3.z, x3.w};
  float acc[16];
  #pragma unroll
  for (int j = 0; j < 16; ++j) acc[j] = 0.f;
  #pragma unroll
  for (int k = 0; k < 16; ++k) {
    const float* wr = W + (size_t)k * 16;
    #pragma unroll
    for (int j = 0; j < 16; ++j)
      acc[j] = fmaf(xv[k], wr[j], acc[j]);
  }
  float dd = dis[row];
  uint4 pa, pb;
  pa.x = f2bf2(acc[0] * dd, acc[1] * dd);
  pa.y = f2bf2(acc[2] * dd, acc[3] * dd);
  pa.z = f2bf2(acc[4] * dd, acc[5] * dd);
  pa.w = f2bf2(acc[6] * dd, acc[7] * dd);
  pb.x = f2bf2(acc[8] * dd, acc[9] * dd);
  pb.y = f2bf2(acc[10] * dd, acc[11] * dd);
  pb.z = f2bf2(acc[12] * dd, acc[13] * dd);
  pb.w = f2bf2(acc[14] * dd, acc[15] * dd);
  uint4* g4 = (uint4*)gb;
  g4[(size_t)row * 2] = pa;
  g4[(size_t)row * 2 + 1] = pb;
}

// ---------------------------------------------------------------- aggregation: 2 nodes per wave
__device__ __forceinline__ void gather8v2(const uint4* gp, const int* __restrict__ col,
                                          int beg, int end, int h, int slot, float* acc) {
  #pragma unroll
  for (int j = 0; j < 8; ++j) acc[j] = 0.f;
  for (int e = beg + slot; e < end; e += 16) {
    int s = col[e];
    uint4 v = gp[(size_t)s * 2 + h];
    acc[0] += bflo(v.x); acc[1] += bfhi(v.x);
    acc[2] += bflo(v.y); acc[3] += bfhi(v.y);
    acc[4] += bflo(v.z); acc[5] += bfhi(v.z);
    acc[6] += bflo(v.w); acc[7] += bfhi(v.w);
  }
  #pragma unroll
  for (int d = 2; d < 32; d <<= 1) {  // slot bits = lane bits 1..4
    #pragma unroll
    for (int j = 0; j < 8; ++j) acc[j] += __shfl_xor(acc[j], d);
  }
}

// layer-1 agg: z = relu(dis*(sum + self) + b1) -> o1 (f32)
__global__ void k_agg1(const unsigned int* __restrict__ gb, const int* __restrict__ col,
                       const int* __restrict__ rowptr, const float* __restrict__ dis,
                       const float* __restrict__ bias, float* __restrict__ o1) {
  int wid = threadIdx.x >> 6;
  int lane = threadIdx.x & 63;
  int n2 = lane >> 5;
  int node = blockIdx.x * 8 + wid * 2 + n2;
  if (node >= NNODES) return;
  int rem = lane & 31;
  int h = rem & 1, slot = rem >> 1;
  const uint4* gp = (const uint4*)gb;
  float acc[8];
  gather8v2(gp, col, rowptr[node], rowptr[node + 1], h, slot, acc);
  uint4 sv = gp[(size_t)node * 2 + h];
  acc[0] += bflo(sv.x); acc[1] += bfhi(sv.x);
  acc[2] += bflo(sv.y); acc[3] += bfhi(sv.y);
  acc[4] += bflo(sv.z); acc[5] += bfhi(sv.z);
  acc[6] += bflo(sv.w); acc[7] += bfhi(sv.w);
  float dd = dis[node];
  const float4* b4 = (const float4*)bias;
  float4 ba = b4[2 * h], bb = b4[2 * h + 1];
  float z0 = fmaxf(fmaf(dd, acc[0], ba.x), 0.f);
  float z1 = fmaxf(fmaf(dd, acc[1], ba.y), 0.f);
  float z2 = fmaxf(fmaf(dd, acc[2], ba.z), 0.f);
  float z3 = fmaxf(fmaf(dd, acc[3], ba.w), 0.f);
  float z4 = fmaxf(fmaf(dd, acc[4], bb.x), 0.f);
  float z5 = fmaxf(fmaf(dd, acc[5], bb.y), 0.f);
  float z6 = fmaxf(fmaf(dd, acc[6], bb.z), 0.f);
  float z7 = fmaxf(fmaf(dd, acc[7], bb.w), 0.f);
  if (slot == 0) {
    float4* o4 = (float4*)o1;
    o4[(size_t)node * 4 + 2 * h] = make_float4(z0, z1, z2, z3);
    o4[(size_t)node * 4 + 2 * h + 1] = make_float4(z4, z5, z6, z7);
  }
}

// layer-2 agg: z = dis*(sum + self) + b2 -> log_softmax -> out (f32)
__global__ void k_agg2(const unsigned int* __restrict__ gb, const int* __restrict__ col,
                       const int* __restrict__ rowptr, const float* __restrict__ dis,
                       const float* __restrict__ bias, float* __restrict__ out) {
  int wid = threadIdx.x >> 6;
  int lane = threadIdx.x & 63;
  int n2 = lane >> 5;
  int node = blockIdx.x * 8 + wid * 2 + n2;
  if (node >= NNODES) return;
  int rem = lane & 31;
  int h = rem & 1, slot = rem >> 1;
  const uint4* gp = (const uint4*)gb;
  float acc[8];
  gather8v2(gp, col, rowptr[node], rowptr[node + 1], h, slot, acc);
  uint4 sv = gp[(size_t)node * 2 + h];
  acc[0] += bflo(sv.x); acc[1] += bfhi(sv.x);
  acc[2] += bflo(sv.y); acc[3] += bfhi(sv.y);
  acc[4] += bflo(sv.z); acc[5] += bfhi(sv.z);
  acc[6] += bflo(sv.w); acc[7] += bfhi(sv.w);
  float dd = dis[node];
  const float4* b4 = (const float4*)bias;
  float4 ba = b4[2 * h], bb = b4[2 * h + 1];
  float z[8];
  z[0] = fmaf(dd, acc[0], ba.x); z[1] = fmaf(dd, acc[1], ba.y);
  z[2] = fmaf(dd, acc[2], ba.z); z[3] = fmaf(dd, acc[3], ba.w);
  z[4] = fmaf(dd, acc[4], bb.x); z[5] = fmaf(dd, acc[5], bb.y);
  z[6] = fmaf(dd, acc[6], bb.z); z[7] = fmaf(dd, acc[7], bb.w);
  float m = z[0];
  #pragma unroll
  for (int j = 1; j < 8; ++j) m = fmaxf(m, z[j]);
  m = fmaxf(m, __shfl_xor(m, 1));  // combine halves (within pair)
  float se = 0.f;
  #pragma unroll
  for (int j = 0; j < 8; ++j) se += expf(z[j] - m);
  se += __shfl_xor(se, 1);
  float lg = m + logf(se);
  if (slot == 0) {
    float4* o4 = (float4*)out;
    o4[(size_t)node * 4 + 2 * h] = make_float4(z[0] - lg, z[1] - lg, z[2] - lg, z[3] - lg);
    o4[(size_t)node * 4 + 2 * h + 1] = make_float4(z[4] - lg, z[5] - lg, z[6] - lg, z[7] - lg);
  }
}

// ---------------------------------------------------------------- launch
extern "C" void kernel_launch(void* const* d_in, const int* in_sizes, int n_in,
                              void* d_out, int out_size, void* d_ws, size_t ws_size,
                              hipStream_t stream) {
  const float* x  = (const float*)d_in[0];
  const void*  ei = d_in[1];
  const float* W1 = (const float*)d_in[2];
  const float* b1 = (const float*)d_in[3];
  const float* W2 = (const float*)d_in[4];
  const float* b2 = (const float*)d_in[5];
  float* out = (float*)d_out;

  const int n = NNODES;
  const int E = in_sizes[1] / 2;

  char* ws = (char*)d_ws;
  size_t off = 0;
  auto alloc = [&](size_t bytes) -> void* {
    void* p = ws + off;
    off = (off + bytes + 255) & ~(size_t)255;
    return p;
  };
  int*            flag   = (int*)            alloc(256);
  int*            gcur   = (int*)            alloc(256);
  int*            sArr   = (int*)            alloc((size_t)NBUCK * CAP * 4);  // 13.1 MB
  unsigned short* dArr   = (unsigned short*) alloc((size_t)NBUCK * CAP * 2);  // 6.5 MB
  int*            cntc   = (int*)            alloc((size_t)NCHUNK * n * 4);   // 12.8 MB
  int*            tot    = (int*)            alloc((size_t)n * 4);
  float*          dis    = (float*)          alloc((size_t)n * 4);
  int*            rowptr = (int*)            alloc((size_t)(n + 1) * 4);
  int*            bsum   = (int*)            alloc(4096);
  int*            col    = (int*)            alloc((size_t)E * 4);            // 12.8 MB
  unsigned short* gb1    = (unsigned short*) alloc((size_t)n * 16 * 2);       // 3.2 MB bf16
  // overlays (dead after k_scatter): o1 (6.4 MB f32) in sArr (13.1 MB); gb2 (3.2 MB) in dArr (6.5 MB)
  float*          o1  = (float*)sArr;
  unsigned int*   gb2 = (unsigned int*)dArr;
  (void)ws_size; (void)n_in; (void)out_size;

  int nb = (n + 255) / 256;  // 391 <= 512
  int binBlocks  = (E + BCHUNK - 1) / BCHUNK;           // 1024 at E=3.2M
  int gemmBlocks = (GTILES + 3) / 4;                    // 782
  int groups = max((gemmBlocks + 2) / 3, (binBlocks + 3) / 4);  // max(261, 256) = 261
  int grid = groups * 7;                                // 1827 blocks = 7.1/CU

  k_init<<<1, 64, 0, stream>>>(ei, flag, gcur);
  k_binmm<<<grid, 256, 0, stream>>>(ei, flag, gcur, sArr, dArr, E, binBlocks,
                                    x, W1, gb1, gemmBlocks);
  k_hist<<<NBUCK * NCHUNK, 256, 0, stream>>>(gcur, dArr, cntc);
  k_dis<<<nb, 256, 0, stream>>>(cntc, tot, dis, bsum, (unsigned int*)gb1, n);
  k_scan_fc<<<nb, 256, 0, stream>>>(tot, bsum, rowptr, cntc, n, nb);
  k_scatter<<<NBUCK * NCHUNK, 256, 0, stream>>>(gcur, sArr, dArr, cntc, col);

  k_agg1<<<(n + 7) / 8, 256, 0, stream>>>((const unsigned int*)gb1, col, rowptr, dis, b1, o1);
  k_gemm2<<<(n + 255) / 256, 256, 0, stream>>>(o1, W2, dis, (unsigned int*)gb2, n);
  k_agg2<<<(n + 7) / 8, 256, 0, stream>>>(gb2, col, rowptr, dis, b2, out);
}

// Round 22
// 197.873 us; speedup vs baseline: 1.2020x; 1.0379x over previous
//
#include <hip/hip_runtime.h>
#include <hip/hip_bf16.h>
#include <math.h>

#define NNODES 100000
#define NBUCK 8
#define XRANGE 12500                 // NNODES / NBUCK
#define NCHUNK 32                    // chunks per bucket for hist/scatter (256 blocks = 1/CU)
#define CAP 408192                   // per-bucket capacity: E/8 + 13 sigma
#define BCHUNK 3125                  // edges per bin-role block: stash 18.8 KB -> 8 blocks/CU LDS cap
#define GT64 1563                    // ceil(100000/64) gemm wave-tiles of 64 rows

typedef __attribute__((ext_vector_type(8))) short bf16x8;  // 8 bf16 = 4 VGPRs
typedef __attribute__((ext_vector_type(4))) float f32x4;

// ---------------------------------------------------------------- bf16 helpers (storage bf16, math f32)
__device__ __forceinline__ float bflo(unsigned int u) {
  union { unsigned int i; float f; } v; v.i = u << 16; return v.f;
}
__device__ __forceinline__ float bfhi(unsigned int u) {
  union { unsigned int i; float f; } v; v.i = u & 0xFFFF0000u; return v.f;
}
__device__ __forceinline__ unsigned int f2bf1(float f) {
  union { float f; unsigned int i; } v; v.f = f;
  return (v.i + 0x7FFFu + ((v.i >> 16) & 1u)) >> 16;  // RNE
}
__device__ __forceinline__ unsigned int f2bf2(float a, float b) {
  return f2bf1(a) | (f2bf1(b) << 16);
}

__device__ __forceinline__ int edge_val(const void* eidx, int is64, size_t i) {
  if (is64) return (int)((const long long*)eidx)[i];
  return ((const int*)eidx)[i];
}

__device__ __forceinline__ bf16x8 cvt8(const float4& p, const float4& q) {
  union { unsigned int u[4]; bf16x8 v; } r;
  r.u[0] = f2bf2(p.x, p.y);
  r.u[1] = f2bf2(p.z, p.w);
  r.u[2] = f2bf2(q.x, q.y);
  r.u[3] = f2bf2(q.z, q.w);
  return r.v;
}

__device__ __forceinline__ bf16x8 cvtW(const float* wf) {
  union { unsigned int u[4]; bf16x8 v; } r;
  r.u[0] = f2bf2(wf[0], wf[1]);
  r.u[1] = f2bf2(wf[2], wf[3]);
  r.u[2] = f2bf2(wf[4], wf[5]);
  r.u[3] = f2bf2(wf[6], wf[7]);
  return r.v;
}

// ---------------------------------------------------------------- init: dtype-detect + zero gcur
__global__ void k_init(const void* eidx, int* flag, int* gcur) {
  int t = threadIdx.x;  // one wave
  int bad = 0;
  const unsigned long long* p = (const unsigned long long*)eidx;
  for (int i = t; i < 1024; i += 64)
    if (p[i] >> 32) bad = 1;
  unsigned long long b = __ballot(bad);
  if (t == 0) flag[0] = (b == 0ULL) ? 1 : 0;
  if (t < NBUCK) gcur[t] = 0;
}

// ---------------------------------------------------------------- FUSED bin || gemm1
// R21 structure (205us best). This round: gemm role widens to 64 rows/wave
// (4 MFMA sub-tiles): per kc 8 x-float4 + 8 W loads in flight feed 4 MFMAs
// (was 4+8 -> 2) => 2x MLP per wave, half the gemm waves, half the W L2
// re-reads. Roles regrouped 11 = 3 gemm + 8 bin; grid 1441 = 5.6 blocks/CU
// (< 8-block LDS cap from the 18.8 KB bin stash).
__global__ void k_binmm(const void* eidx, const int* __restrict__ flag, int* gcur,
                        int* __restrict__ sArr, unsigned short* __restrict__ dArr,
                        int E, int binBlocks,
                        const float* __restrict__ x, const float* __restrict__ W,
                        unsigned short* __restrict__ gb, int gemmBlocks) {
  __shared__ unsigned int s_sb[BCHUNK];    // bin: s | bk<<17  (12.5 KB)
  __shared__ unsigned short s_dl[BCHUNK];  // bin: d - bk*XRANGE (6.25 KB)
  __shared__ int bbase[NBUCK], lcur[NBUCK], wcnt[4][NBUCK];

  int grp = blockIdx.x / 11, role = blockIdx.x % 11;
  if (role < 3) {
    // ---------------- gemm1 role: 64 rows/wave (unscaled output) ----------------
    int gid = grp * 3 + role;
    if (gid >= gemmBlocks) return;
    int wid = threadIdx.x >> 6;
    int tile = gid * 4 + wid;
    if (tile >= GT64) return;
    int lane = threadIdx.x & 63;
    int row0 = tile * 64;
    int q8 = lane >> 4;           // k-octet selector (0..3)
    int jm = lane & 15;           // B col j == A row-in-tile m
    const float4* x4 = (const float4*)x;
    // clamped row bases (tail tile 1562 spans rows >= NNODES)
    size_t xb0 = (size_t)min(row0 + jm,      NNODES - 1) * 128 + q8 * 2;
    size_t xb1 = (size_t)min(row0 + 16 + jm, NNODES - 1) * 128 + q8 * 2;
    size_t xb2 = (size_t)min(row0 + 32 + jm, NNODES - 1) * 128 + q8 * 2;
    size_t xb3 = (size_t)min(row0 + 48 + jm, NNODES - 1) * 128 + q8 * 2;

    f32x4 acc0 = {0.f, 0.f, 0.f, 0.f}, acc1 = {0.f, 0.f, 0.f, 0.f};
    f32x4 acc2 = {0.f, 0.f, 0.f, 0.f}, acc3 = {0.f, 0.f, 0.f, 0.f};
    #pragma unroll
    for (int kc = 0; kc < 16; ++kc) {
      // 8 x-float4 + 8 W loads issue together -> 16 in flight, one wait, 4 MFMAs
      float4 va0 = x4[xb0 + kc * 8], va1 = x4[xb0 + kc * 8 + 1];
      float4 vb0 = x4[xb1 + kc * 8], vb1 = x4[xb1 + kc * 8 + 1];
      float4 vc0 = x4[xb2 + kc * 8], vc1 = x4[xb2 + kc * 8 + 1];
      float4 vd0 = x4[xb3 + kc * 8], vd1 = x4[xb3 + kc * 8 + 1];
      float wf[8];
      #pragma unroll
      for (int i = 0; i < 8; ++i)
        wf[i] = W[(size_t)(kc * 32 + q8 * 8 + i) * 16 + jm];
      bf16x8 bfr = cvtW(wf);
      acc0 = __builtin_amdgcn_mfma_f32_16x16x32_bf16(cvt8(va0, va1), bfr, acc0, 0, 0, 0);
      acc1 = __builtin_amdgcn_mfma_f32_16x16x32_bf16(cvt8(vb0, vb1), bfr, acc1, 0, 0, 0);
      acc2 = __builtin_amdgcn_mfma_f32_16x16x32_bf16(cvt8(vc0, vc1), bfr, acc2, 0, 0, 0);
      acc3 = __builtin_amdgcn_mfma_f32_16x16x32_bf16(cvt8(vd0, vd1), bfr, acc3, 0, 0, 0);
    }
    // unscaled epilogue: D[row = t*16 + q8*4 + r][jm], guarded for the tail tile
    #pragma unroll
    for (int r = 0; r < 4; ++r) {
      int rl = q8 * 4 + r;
      int w0 = row0 + rl, w1 = row0 + 16 + rl, w2 = row0 + 32 + rl, w3 = row0 + 48 + rl;
      if (w0 < NNODES) gb[(size_t)w0 * 16 + jm] = (unsigned short)f2bf1(acc0[r]);
      if (w1 < NNODES) gb[(size_t)w1 * 16 + jm] = (unsigned short)f2bf1(acc1[r]);
      if (w2 < NNODES) gb[(size_t)w2 * 16 + jm] = (unsigned short)f2bf1(acc2[r]);
      if (w3 < NNODES) gb[(size_t)w3 * 16 + jm] = (unsigned short)f2bf1(acc3[r]);
    }
    return;
  }

  // ---------------- bin role (LDS stash, single global edge read) ----------------
  int bid = grp * 8 + (role - 3);
  if (bid >= binBlocks) return;
  int is64 = flag[0];
  int beg = bid * BCHUNK;
  int end = min(beg + BCHUNK, E);
  int cnt = end - beg;
  int lane = threadIdx.x & 63, wid = threadIdx.x >> 6;

  // phase A: read edges once, stash to LDS, ballot-count per wave
  int cl = 0;
  for (int i = threadIdx.x; i < cnt; i += 256) {
    int e = beg + i;
    int s = edge_val(eidx, is64, e);
    int d = edge_val(eidx, is64, (size_t)E + e);
    int bk = d / XRANGE;
    s_sb[i] = (unsigned int)s | ((unsigned int)bk << 17);
    s_dl[i] = (unsigned short)(d - bk * XRANGE);
    #pragma unroll
    for (int b = 0; b < NBUCK; ++b) {
      unsigned long long m = __ballot(bk == b);
      if (lane == b) cl += __popcll(m);   // low lanes exit the loop last
    }
  }
  if (lane < NBUCK) wcnt[wid][lane] = cl;
  __syncthreads();
  if (threadIdx.x < NBUCK) {
    int t = wcnt[0][threadIdx.x] + wcnt[1][threadIdx.x] +
            wcnt[2][threadIdx.x] + wcnt[3][threadIdx.x];
    bbase[threadIdx.x] = atomicAdd(&gcur[threadIdx.x], t);
    lcur[threadIdx.x] = 0;
  }
  __syncthreads();

  // phase B: ballot-rank placement from LDS
  for (int i = threadIdx.x; i < cnt; i += 256) {
    unsigned int sb = s_sb[i];
    int bk = (int)(sb >> 17);
    int s = (int)(sb & 0x1FFFFu);
    unsigned short dl = s_dl[i];
    #pragma unroll
    for (int b = 0; b < NBUCK; ++b) {
      unsigned long long m = __ballot(bk == b);
      int c = __popcll(m);
      if (!c) continue;
      int leader = __ffsll((unsigned long long)m) - 1;
      int base = 0;
      if (lane == leader) base = atomicAdd(&lcur[b], c);  // LDS atomic
      base = __shfl(base, leader);
      if (bk == b) {
        int rank = __popcll(m & ((1ULL << lane) - 1));
        int gpos = bbase[b] + base + rank;
        if (gpos < CAP) {
          sArr[(size_t)b * CAP + gpos] = s;
          dArr[(size_t)b * CAP + gpos] = dl;
        }
      }
    }
  }
}

// ---------------------------------------------------------------- histogram (LDS, no device atomics)
__global__ void k_hist(const int* __restrict__ gcur, const unsigned short* __restrict__ dArr,
                       int* __restrict__ cntc) {
  int b = blockIdx.x & (NBUCK - 1);
  int c = blockIdx.x >> 3;
  __shared__ int h[XRANGE];
  for (int i = threadIdx.x; i < XRANGE; i += 256) h[i] = 0;
  __syncthreads();
  int nE = min(gcur[b], CAP);
  int ce = (nE + NCHUNK - 1) / NCHUNK;
  int beg = c * ce, end = min(beg + ce, nE);
  const unsigned short* dp = dArr + (size_t)b * CAP;
  for (int e = beg + threadIdx.x; e < end; e += 256)
    atomicAdd(&h[dp[e]], 1);
  __syncthreads();
  int lo = b * XRANGE;
  for (int i = threadIdx.x; i < XRANGE; i += 256)
    cntc[(size_t)c * NNODES + lo + i] = h[i];
}

// ---------------------------------------------------------------- degree -> dis, and SCALE gb1 in place
__global__ void k_dis(const int* __restrict__ cntc, int* __restrict__ tot,
                      float* __restrict__ dis, int* __restrict__ bsum,
                      unsigned int* __restrict__ gb1, int n) {
  int i = blockIdx.x * 256 + threadIdx.x;
  int t = 0;
  if (i < n) {
    #pragma unroll
    for (int c = 0; c < NCHUNK; ++c) t += cntc[(size_t)c * NNODES + i];
    tot[i] = t;
    float dd = rsqrtf((float)(t + 1));  // +1 = self loop
    dis[i] = dd;
    uint4* g4 = (uint4*)gb1;
    uint4 pa = g4[(size_t)i * 2], pb = g4[(size_t)i * 2 + 1];
    pa.x = f2bf2(bflo(pa.x) * dd, bfhi(pa.x) * dd);
    pa.y = f2bf2(bflo(pa.y) * dd, bfhi(pa.y) * dd);
    pa.z = f2bf2(bflo(pa.z) * dd, bfhi(pa.z) * dd);
    pa.w = f2bf2(bflo(pa.w) * dd, bfhi(pa.w) * dd);
    pb.x = f2bf2(bflo(pb.x) * dd, bfhi(pb.x) * dd);
    pb.y = f2bf2(bflo(pb.y) * dd, bfhi(pb.y) * dd);
    pb.z = f2bf2(bflo(pb.z) * dd, bfhi(pb.z) * dd);
    pb.w = f2bf2(bflo(pb.w) * dd, bfhi(pb.w) * dd);
    g4[(size_t)i * 2] = pa;
    g4[(size_t)i * 2 + 1] = pb;
  }
  int v = t;
  #pragma unroll
  for (int d = 32; d > 0; d >>= 1) v += __shfl_down(v, d);
  __shared__ int ws4[4];
  if ((threadIdx.x & 63) == 0) ws4[threadIdx.x >> 6] = v;
  __syncthreads();
  if (threadIdx.x == 0) bsum[blockIdx.x] = ws4[0] + ws4[1] + ws4[2] + ws4[3];
}

// fused scan: every block replicates the 391-entry partials scan, then its
// per-node local scan, then walks the 32 chunk planes into cursor bases.
__global__ void k_scan_fc(const int* __restrict__ tot, const int* __restrict__ bsum,
                          int* __restrict__ rowptr, int* __restrict__ cntc, int n, int nb) {
  __shared__ int ps[512];
  __shared__ int s[256];
  int t = threadIdx.x;
  ps[t] = (t < nb) ? bsum[t] : 0;
  ps[t + 256] = (t + 256 < nb) ? bsum[t + 256] : 0;
  __syncthreads();
  for (int d = 1; d < 512; d <<= 1) {
    int u0 = (t >= d) ? ps[t - d] : 0;
    int u1 = (t + 256 >= d) ? ps[t + 256 - d] : 0;
    __syncthreads();
    ps[t] += u0;
    ps[t + 256] += u1;
    __syncthreads();
  }
  int bex = (blockIdx.x == 0) ? 0 : ps[blockIdx.x - 1];
  if (blockIdx.x == 0 && t == 0) rowptr[n] = ps[nb - 1];  // total

  int idx = blockIdx.x * 256 + t;
  int v = (idx < n) ? tot[idx] : 0;
  s[t] = v;
  __syncthreads();
  for (int d = 1; d < 256; d <<= 1) {
    int u = (t >= d) ? s[t - d] : 0;
    __syncthreads();
    s[t] += u;
    __syncthreads();
  }
  if (idx < n) {
    int run = bex + s[t] - v;
    rowptr[idx] = run;
    #pragma unroll
    for (int c = 0; c < NCHUNK; ++c) {
      size_t id2 = (size_t)c * NNODES + idx;
      int tc = cntc[id2];
      cntc[id2] = run;
      run += tc;
    }
  }
}

// ---------------------------------------------------------------- scatter (LDS cursors)
__global__ void k_scatter(const int* __restrict__ gcur, const int* __restrict__ sArr,
                          const unsigned short* __restrict__ dArr,
                          const int* __restrict__ cntc, int* __restrict__ col) {
  int b = blockIdx.x & (NBUCK - 1);
  int c = blockIdx.x >> 3;
  __shared__ int cur[XRANGE];
  int lo = b * XRANGE;
  for (int i = threadIdx.x; i < XRANGE; i += 256)
    cur[i] = cntc[(size_t)c * NNODES + lo + i];
  __syncthreads();
  int nE = min(gcur[b], CAP);
  int ce = (nE + NCHUNK - 1) / NCHUNK;
  int beg = c * ce, end = min(beg + ce, nE);
  const int* sp = sArr + (size_t)b * CAP;
  const unsigned short* dp = dArr + (size_t)b * CAP;
  for (int e = beg + threadIdx.x; e < end; e += 256) {
    int d = dp[e];
    int pos = atomicAdd(&cur[d], 1);  // LDS atomic
    col[pos] = sp[e];
  }
}

// ---------------------------------------------------------------- GEMM2: o1[100K,16] @ W2 -> gb2 (bf16, pre-scaled)
__global__ void k_gemm2(const float* __restrict__ o1, const float* __restrict__ W,
                        const float* __restrict__ dis, unsigned int* __restrict__ gb, int nrows) {
  int row = blockIdx.x * blockDim.x + threadIdx.x;
  if (row >= nrows) return;
  const float4* xr = (const float4*)(o1 + (size_t)row * 16);
  float4 x0 = xr[0], x1 = xr[1], x2 = xr[2], x3 = xr[3];
  float xv[16] = {x0.x, x0.y, x0.z, x0.w, x1.x, x1.y, x1.z, x1.w,
                  x2.x, x2.y, x2.z, x2.w, x3.x, x3.y, x3.z, x3.w};
  float acc[16];
  #pragma unroll
  for (int j = 0; j < 16; ++j) acc[j] = 0.f;
  #pragma unroll
  for (int k = 0; k < 16; ++k) {
    const float* wr = W + (size_t)k * 16;
    #pragma unroll
    for (int j = 0; j < 16; ++j)
      acc[j] = fmaf(xv[k], wr[j], acc[j]);
  }
  float dd = dis[row];
  uint4 pa, pb;
  pa.x = f2bf2(acc[0] * dd, acc[1] * dd);
  pa.y = f2bf2(acc[2] * dd, acc[3] * dd);
  pa.z = f2bf2(acc[4] * dd, acc[5] * dd);
  pa.w = f2bf2(acc[6] * dd, acc[7] * dd);
  pb.x = f2bf2(acc[8] * dd, acc[9] * dd);
  pb.y = f2bf2(acc[10] * dd, acc[11] * dd);
  pb.z = f2bf2(acc[12] * dd, acc[13] * dd);
  pb.w = f2bf2(acc[14] * dd, acc[15] * dd);
  uint4* g4 = (uint4*)gb;
  g4[(size_t)row * 2] = pa;
  g4[(size_t)row * 2 + 1] = pb;
}

// ---------------------------------------------------------------- aggregation: 2 nodes per wave
__device__ __forceinline__ void gather8v2(const uint4* gp, const int* __restrict__ col,
                                          int beg, int end, int h, int slot, float* acc) {
  #pragma unroll
  for (int j = 0; j < 8; ++j) acc[j] = 0.f;
  for (int e = beg + slot; e < end; e += 16) {
    int s = col[e];
    uint4 v = gp[(size_t)s * 2 + h];
    acc[0] += bflo(v.x); acc[1] += bfhi(v.x);
    acc[2] += bflo(v.y); acc[3] += bfhi(v.y);
    acc[4] += bflo(v.z); acc[5] += bfhi(v.z);
    acc[6] += bflo(v.w); acc[7] += bfhi(v.w);
  }
  #pragma unroll
  for (int d = 2; d < 32; d <<= 1) {  // slot bits = lane bits 1..4
    #pragma unroll
    for (int j = 0; j < 8; ++j) acc[j] += __shfl_xor(acc[j], d);
  }
}

// layer-1 agg: z = relu(dis*(sum + self) + b1) -> o1 (f32)
__global__ void k_agg1(const unsigned int* __restrict__ gb, const int* __restrict__ col,
                       const int* __restrict__ rowptr, const float* __restrict__ dis,
                       const float* __restrict__ bias, float* __restrict__ o1) {
  int wid = threadIdx.x >> 6;
  int lane = threadIdx.x & 63;
  int n2 = lane >> 5;
  int node = blockIdx.x * 8 + wid * 2 + n2;
  if (node >= NNODES) return;
  int rem = lane & 31;
  int h = rem & 1, slot = rem >> 1;
  const uint4* gp = (const uint4*)gb;
  float acc[8];
  gather8v2(gp, col, rowptr[node], rowptr[node + 1], h, slot, acc);
  uint4 sv = gp[(size_t)node * 2 + h];
  acc[0] += bflo(sv.x); acc[1] += bfhi(sv.x);
  acc[2] += bflo(sv.y); acc[3] += bfhi(sv.y);
  acc[4] += bflo(sv.z); acc[5] += bfhi(sv.z);
  acc[6] += bflo(sv.w); acc[7] += bfhi(sv.w);
  float dd = dis[node];
  const float4* b4 = (const float4*)bias;
  float4 ba = b4[2 * h], bb = b4[2 * h + 1];
  float z0 = fmaxf(fmaf(dd, acc[0], ba.x), 0.f);
  float z1 = fmaxf(fmaf(dd, acc[1], ba.y), 0.f);
  float z2 = fmaxf(fmaf(dd, acc[2], ba.z), 0.f);
  float z3 = fmaxf(fmaf(dd, acc[3], ba.w), 0.f);
  float z4 = fmaxf(fmaf(dd, acc[4], bb.x), 0.f);
  float z5 = fmaxf(fmaf(dd, acc[5], bb.y), 0.f);
  float z6 = fmaxf(fmaf(dd, acc[6], bb.z), 0.f);
  float z7 = fmaxf(fmaf(dd, acc[7], bb.w), 0.f);
  if (slot == 0) {
    float4* o4 = (float4*)o1;
    o4[(size_t)node * 4 + 2 * h] = make_float4(z0, z1, z2, z3);
    o4[(size_t)node * 4 + 2 * h + 1] = make_float4(z4, z5, z6, z7);
  }
}

// layer-2 agg: z = dis*(sum + self) + b2 -> log_softmax -> out (f32)
__global__ void k_agg2(const unsigned int* __restrict__ gb, const int* __restrict__ col,
                       const int* __restrict__ rowptr, const float* __restrict__ dis,
                       const float* __restrict__ bias, float* __restrict__ out) {
  int wid = threadIdx.x >> 6;
  int lane = threadIdx.x & 63;
  int n2 = lane >> 5;
  int node = blockIdx.x * 8 + wid * 2 + n2;
  if (node >= NNODES) return;
  int rem = lane & 31;
  int h = rem & 1, slot = rem >> 1;
  const uint4* gp = (const uint4*)gb;
  float acc[8];
  gather8v2(gp, col, rowptr[node], rowptr[node + 1], h, slot, acc);
  uint4 sv = gp[(size_t)node * 2 + h];
  acc[0] += bflo(sv.x); acc[1] += bfhi(sv.x);
  acc[2] += bflo(sv.y); acc[3] += bfhi(sv.y);
  acc[4] += bflo(sv.z); acc[5] += bfhi(sv.z);
  acc[6] += bflo(sv.w); acc[7] += bfhi(sv.w);
  float dd = dis[node];
  const float4* b4 = (const float4*)bias;
  float4 ba = b4[2 * h], bb = b4[2 * h + 1];
  float z[8];
  z[0] = fmaf(dd, acc[0], ba.x); z[1] = fmaf(dd, acc[1], ba.y);
  z[2] = fmaf(dd, acc[2], ba.z); z[3] = fmaf(dd, acc[3], ba.w);
  z[4] = fmaf(dd, acc[4], bb.x); z[5] = fmaf(dd, acc[5], bb.y);
  z[6] = fmaf(dd, acc[6], bb.z); z[7] = fmaf(dd, acc[7], bb.w);
  float m = z[0];
  #pragma unroll
  for (int j = 1; j < 8; ++j) m = fmaxf(m, z[j]);
  m = fmaxf(m, __shfl_xor(m, 1));  // combine halves (within pair)
  float se = 0.f;
  #pragma unroll
  for (int j = 0; j < 8; ++j) se += expf(z[j] - m);
  se += __shfl_xor(se, 1);
  float lg = m + logf(se);
  if (slot == 0) {
    float4* o4 = (float4*)out;
    o4[(size_t)node * 4 + 2 * h] = make_float4(z[0] - lg, z[1] - lg, z[2] - lg, z[3] - lg);
    o4[(size_t)node * 4 + 2 * h + 1] = make_float4(z[4] - lg, z[5] - lg, z[6] - lg, z[7] - lg);
  }
}

// ---------------------------------------------------------------- launch
extern "C" void kernel_launch(void* const* d_in, const int* in_sizes, int n_in,
                              void* d_out, int out_size, void* d_ws, size_t ws_size,
                              hipStream_t stream) {
  const float* x  = (const float*)d_in[0];
  const void*  ei = d_in[1];
  const float* W1 = (const float*)d_in[2];
  const float* b1 = (const float*)d_in[3];
  const float* W2 = (const float*)d_in[4];
  const float* b2 = (const float*)d_in[5];
  float* out = (float*)d_out;

  const int n = NNODES;
  const int E = in_sizes[1] / 2;

  char* ws = (char*)d_ws;
  size_t off = 0;
  auto alloc = [&](size_t bytes) -> void* {
    void* p = ws + off;
    off = (off + bytes + 255) & ~(size_t)255;
    return p;
  };
  int*            flag   = (int*)            alloc(256);
  int*            gcur   = (int*)            alloc(256);
  int*            sArr   = (int*)            alloc((size_t)NBUCK * CAP * 4);  // 13.1 MB
  unsigned short* dArr   = (unsigned short*) alloc((size_t)NBUCK * CAP * 2);  // 6.5 MB
  int*            cntc   = (int*)            alloc((size_t)NCHUNK * n * 4);   // 12.8 MB
  int*            tot    = (int*)            alloc((size_t)n * 4);
  float*          dis    = (float*)          alloc((size_t)n * 4);
  int*            rowptr = (int*)            alloc((size_t)(n + 1) * 4);
  int*            bsum   = (int*)            alloc(4096);
  int*            col    = (int*)            alloc((size_t)E * 4);            // 12.8 MB
  unsigned short* gb1    = (unsigned short*) alloc((size_t)n * 16 * 2);       // 3.2 MB bf16
  // overlays (dead after k_scatter): o1 (6.4 MB f32) in sArr (13.1 MB); gb2 (3.2 MB) in dArr (6.5 MB)
  float*          o1  = (float*)sArr;
  unsigned int*   gb2 = (unsigned int*)dArr;
  (void)ws_size; (void)n_in; (void)out_size;

  int nb = (n + 255) / 256;  // 391 <= 512
  int binBlocks  = (E + BCHUNK - 1) / BCHUNK;           // 1024 at E=3.2M
  int gemmBlocks = (GT64 + 3) / 4;                      // 391
  int groups = max((gemmBlocks + 2) / 3, (binBlocks + 7) / 8);  // max(131, 128) = 131
  int grid = groups * 11;                               // 1441 blocks = 5.6/CU

  k_init<<<1, 64, 0, stream>>>(ei, flag, gcur);
  k_binmm<<<grid, 256, 0, stream>>>(ei, flag, gcur, sArr, dArr, E, binBlocks,
                                    x, W1, gb1, gemmBlocks);
  k_hist<<<NBUCK * NCHUNK, 256, 0, stream>>>(gcur, dArr, cntc);
  k_dis<<<nb, 256, 0, stream>>>(cntc, tot, dis, bsum, (unsigned int*)gb1, n);
  k_scan_fc<<<nb, 256, 0, stream>>>(tot, bsum, rowptr, cntc, n, nb);
  k_scatter<<<NBUCK * NCHUNK, 256, 0, stream>>>(gcur, sArr, dArr, cntc, col);

  k_agg1<<<(n + 7) / 8, 256, 0, stream>>>((const unsigned int*)gb1, col, rowptr, dis, b1, o1);
  k_gemm2<<<(n + 255) / 256, 256, 0, stream>>>(o1, W2, dis, (unsigned int*)gb2, n);
  k_agg2<<<(n + 7) / 8, 256, 0, stream>>>(gb2, col, rowptr, dis, b2, out);
}